// Round 3
// baseline (812.981 us; speedup 1.0000x reference)
//
#include <hip/hip_runtime.h>

// EGNN layer (round 3): inputs/outputs are FLOAT32 per the reference dtypes
// (rounds 1-2 misread them as bf16 -> NaN from garbage exponents through exp).
// Compute path: gather f32 -> convert to bf16 LDS tiles -> MFMA (f32 accum) ->
// f32 epilogues. agg/coord_agg accumulate directly in d_out (f32 atomics),
// node_k finishes in place; ws use = cnt (200 KB) + transposed weights (229 KB).

#define NN 50000
#define NE 800000
#define LDST 136

typedef __bf16 bf16_t;
typedef __bf16 bf16x8 __attribute__((ext_vector_type(8)));
typedef float f32x4 __attribute__((ext_vector_type(4)));

__device__ __forceinline__ float siluf(float v) { return v / (1.f + __expf(-v)); }

// One wave computes a 16-row x 128-col C stripe: C += A(16x128) @ B(128x128).
// A in LDS row-major stride LDST (Arow pre-offset to (m0+cix)*LDST),
// B in LDS transposed [n][k] stride LDST (Bcol pre-offset to cix*LDST).
__device__ __forceinline__ void gemm_stripe(const bf16_t* Arow, const bf16_t* Bcol,
                                            int koff, f32x4 acc[8]) {
#pragma unroll
  for (int ks = 0; ks < 4; ++ks) {
    bf16x8 a = *(const bf16x8*)(Arow + ks * 32 + koff);
#pragma unroll
    for (int nt = 0; nt < 8; ++nt) {
      bf16x8 b = *(const bf16x8*)(Bcol + nt * 16 * LDST + ks * 32 + koff);
      acc[nt] = __builtin_amdgcn_mfma_f32_16x16x32_bf16(a, b, acc[nt], 0, 0, 0);
    }
  }
}

__device__ __forceinline__ void load_B(bf16_t* Bsb, const bf16_t* __restrict__ src, int t) {
  for (int i = t; i < 2048; i += 256) {
    int n = i >> 4, cc = i & 15;
    *(bf16x8*)(Bsb + n * LDST + cc * 8) = *(const bf16x8*)(src + n * 128 + cc * 8);
  }
}

__device__ __forceinline__ bf16x8 cvt8(float4 u0, float4 u1) {
  bf16x8 v;
  v[0] = (bf16_t)u0.x; v[1] = (bf16_t)u0.y; v[2] = (bf16_t)u0.z; v[3] = (bf16_t)u0.w;
  v[4] = (bf16_t)u1.x; v[5] = (bf16_t)u1.y; v[6] = (bf16_t)u1.z; v[7] = (bf16_t)u1.w;
  return v;
}

// gather 64 rows of f32 h (indices in idx_s) into bf16 LDS tile
__device__ __forceinline__ void gather64(bf16_t* dst, const float* __restrict__ h,
                                         const int* idx_s, int t) {
  for (int i = t; i < 1024; i += 256) {
    int rowl = i >> 4, cc = i & 15;
    int node = idx_s[rowl];
    const float4* p = (const float4*)(h + (size_t)node * 128 + cc * 8);
    *(bf16x8*)(dst + rowl * LDST + cc * 8) = cvt8(p[0], p[1]);
  }
}

// ---- transpose 7 128x128 f32 weight blocks into bf16 wt ([n][k] layout) ----
// slots: 0 W1a_t, 1 W1b_t, 2 e_w2t, 3 n_w1a_t, 4 n_w1b_t, 5 n_w2t, 6 c_w1t
__global__ __launch_bounds__(256) void transpose_k(
    const float* __restrict__ e_w1, const float* __restrict__ e_w2,
    const float* __restrict__ n_w1, const float* __restrict__ n_w2,
    const float* __restrict__ c_w1, bf16_t* __restrict__ wt) {
  int b = blockIdx.x;
  const float* src;
  switch (b) {
    case 0: src = e_w1; break;
    case 1: src = e_w1 + 16384; break;
    case 2: src = e_w2; break;
    case 3: src = n_w1; break;
    case 4: src = n_w1 + 16384; break;
    case 5: src = n_w2; break;
    default: src = c_w1; break;
  }
  bf16_t* dst = wt + b * 16384;
  for (int i = threadIdx.x; i < 16384; i += 256) {
    int k = i >> 7, n = i & 127;
    dst[n * 128 + k] = (bf16_t)src[k * 128 + n];
  }
}

// ---- edge kernel: 64 edges per block ----
__global__ __launch_bounds__(256) void edge_k(
    const float* __restrict__ h, const int* __restrict__ ei,
    const float* __restrict__ eattr, const float* __restrict__ x,
    const bf16_t* __restrict__ wt, const float* __restrict__ e_w1,
    const float* __restrict__ e_b1, const float* __restrict__ e_b2,
    const float* __restrict__ c_b1, const float* __restrict__ c_w2,
    const float* __restrict__ a_w, const float* __restrict__ a_b,
    float* __restrict__ agg, float* __restrict__ coord_agg, float* __restrict__ cnt) {
  __shared__ __align__(16) bf16_t Ag[64 * LDST];
  __shared__ __align__(16) bf16_t Bsb[128 * LDST];
  __shared__ int rows_s[64];
  __shared__ int cols_s[64];
  __shared__ float cd_s[64][3];
  __shared__ float rad_s[64];
  __shared__ float ea_s[64];

  int t = threadIdx.x;
  int e0 = blockIdx.x * 64;

  if (t < 64) {
    int eg = e0 + t;
    int r = ei[eg], c = ei[NE + eg];
    rows_s[t] = r; cols_s[t] = c;
    float d0 = x[r * 3 + 0] - x[c * 3 + 0];
    float d1 = x[r * 3 + 1] - x[c * 3 + 1];
    float d2 = x[r * 3 + 2] - x[c * 3 + 2];
    cd_s[t][0] = d0; cd_s[t][1] = d1; cd_s[t][2] = d2;
    rad_s[t] = d0 * d0 + d1 * d1 + d2 * d2;
    ea_s[t] = eattr[eg];
  }
  load_B(Bsb, wt + 0 * 16384, t);  // W1a_t
  __syncthreads();

  gather64(Ag, h, rows_s, t);      // h[row] tile (f32 -> bf16)
  __syncthreads();

  int lane = t & 63, w = t >> 6;
  int m0 = w * 16, quad = lane >> 4, cix = lane & 15, koff = quad * 8;
  const bf16_t* Arow = Ag + (m0 + cix) * LDST;
  const bf16_t* Bcol = Bsb + cix * LDST;

  f32x4 acc[8];
#pragma unroll
  for (int i = 0; i < 8; ++i) acc[i] = (f32x4){0.f, 0.f, 0.f, 0.f};
  gemm_stripe(Arow, Bcol, koff, acc);  // h[row] @ W1a

  __syncthreads();                     // all Ag/Bsb reads done
  gather64(Ag, h, cols_s, t);          // h[col] tile
  load_B(Bsb, wt + 1 * 16384, t);      // W1b_t
  __syncthreads();
  gemm_stripe(Arow, Bcol, koff, acc);  // += h[col] @ W1b

  // z1 = silu(acc + b1 + rad*w_rad + ea*w_ea)  -> Ag (C-layout rows, wave-local)
  {
    const float* w_rad = e_w1 + 256 * 128;
    const float* w_ea = e_w1 + 257 * 128;
#pragma unroll
    for (int nt = 0; nt < 8; ++nt) {
      int colg = nt * 16 + cix;
      float b1v = e_b1[colg];
      float wrv = w_rad[colg];
      float wev = w_ea[colg];
#pragma unroll
      for (int rix = 0; rix < 4; ++rix) {
        int rowl = m0 + quad * 4 + rix;
        float z = acc[nt][rix] + b1v + rad_s[rowl] * wrv + ea_s[rowl] * wev;
        Ag[rowl * LDST + colg] = (bf16_t)siluf(z);
      }
    }
  }
  __syncthreads();
  load_B(Bsb, wt + 2 * 16384, t);  // e_w2t
  __syncthreads();

#pragma unroll
  for (int i = 0; i < 8; ++i) acc[i] = (f32x4){0.f, 0.f, 0.f, 0.f};
  gemm_stripe(Arow, Bcol, koff, acc);  // z1 @ e_w2

  // m = silu(. + b2); att = sigmoid(m . a_w + a_b); m *= att; m -> Ag
  float attp[4] = {0.f, 0.f, 0.f, 0.f};
#pragma unroll
  for (int nt = 0; nt < 8; ++nt) {
    int colg = nt * 16 + cix;
    float b2v = e_b2[colg];
    float awv = a_w[colg];
#pragma unroll
    for (int rix = 0; rix < 4; ++rix) {
      float v = siluf(acc[nt][rix] + b2v);
      acc[nt][rix] = v;
      attp[rix] += v * awv;
    }
  }
  float a_bv = a_b[0];
  float attv[4];
#pragma unroll
  for (int rix = 0; rix < 4; ++rix) {
    float s = attp[rix];
    s += __shfl_xor(s, 1); s += __shfl_xor(s, 2);
    s += __shfl_xor(s, 4); s += __shfl_xor(s, 8);
    attv[rix] = 1.f / (1.f + __expf(-(s + a_bv)));
  }
#pragma unroll
  for (int nt = 0; nt < 8; ++nt) {
#pragma unroll
    for (int rix = 0; rix < 4; ++rix) {
      float v = acc[nt][rix] * attv[rix];
      Ag[(m0 + quad * 4 + rix) * LDST + nt * 16 + cix] = (bf16_t)v;
    }
  }

  __syncthreads();                 // all m rows written; Bsb readers done
  load_B(Bsb, wt + 6 * 16384, t);  // c_w1t
  __syncthreads();

#pragma unroll
  for (int i = 0; i < 8; ++i) acc[i] = (f32x4){0.f, 0.f, 0.f, 0.f};
  gemm_stripe(Arow, Bcol, koff, acc);  // m @ c_w1

  float cup[4] = {0.f, 0.f, 0.f, 0.f};
#pragma unroll
  for (int nt = 0; nt < 8; ++nt) {
    int colg = nt * 16 + cix;
    float cb1v = c_b1[colg];
    float cw2v = c_w2[colg];
#pragma unroll
    for (int rix = 0; rix < 4; ++rix) {
      cup[rix] += siluf(acc[nt][rix] + cb1v) * cw2v;
    }
  }
#pragma unroll
  for (int rix = 0; rix < 4; ++rix) {
    float s = cup[rix];
    s += __shfl_xor(s, 1); s += __shfl_xor(s, 2);
    s += __shfl_xor(s, 4); s += __shfl_xor(s, 8);
    cup[rix] = s;
  }
  if (cix == 0) {
#pragma unroll
    for (int rix = 0; rix < 4; ++rix) {
      int e = m0 + quad * 4 + rix;
      int node = rows_s[e];
      float cu = cup[rix];
      atomicAdd(&coord_agg[node * 3 + 0], cd_s[e][0] * cu);
      atomicAdd(&coord_agg[node * 3 + 1], cd_s[e][1] * cu);
      atomicAdd(&coord_agg[node * 3 + 2], cd_s[e][2] * cu);
      atomicAdd(&cnt[node], 1.0f);
    }
  }

  // scatter gated m into agg (f32 atomics)
#pragma unroll
  for (int it = 0; it < 32; ++it) {
    int idx = it * 256 + t;
    int e = idx >> 7, f = idx & 127;
    float v = (float)Ag[e * LDST + f];
    atomicAdd(&agg[(size_t)rows_s[e] * 128 + f], v);
  }
}

// ---- node kernel (in-place on d_out): ----
// h_out = h + silu(h@n_w1a + agg@n_w1b + n_b1) @ n_w2 + n_b2 ; x_out = x + coord/cnt
__global__ __launch_bounds__(256) void node_k(
    const float* __restrict__ h, const float* __restrict__ x,
    const bf16_t* __restrict__ wt, const float* __restrict__ n_b1,
    const float* __restrict__ n_b2, const float* __restrict__ cnt,
    float* __restrict__ out) {
  __shared__ __align__(16) bf16_t Asb[64 * LDST];
  __shared__ __align__(16) bf16_t Bsb[128 * LDST];
  int t = threadIdx.x;
  int node0 = blockIdx.x * 64;
  const float* agg = out;                          // accumulated by edge_k
  float* xout = out + (size_t)NN * 128;            // holds coord_agg on entry

  // x_out = x + coord_agg / max(cnt,1)   (read-then-write same slot, same thread)
  if (t < 192) {
    int node = node0 + t / 3;
    int d = t - (t / 3) * 3;
    if (node < NN) {
      float c = cnt[node];
      float denom = c > 1.f ? c : 1.f;
      float xo = x[node * 3 + d] + xout[node * 3 + d] / denom;
      xout[node * 3 + d] = xo;
    }
  }

  // stage h tile (f32 -> bf16)
  for (int i = t; i < 1024; i += 256) {
    int rowl = i >> 4, cc = i & 15;
    int node = node0 + rowl; if (node >= NN) node = NN - 1;
    const float4* p = (const float4*)(h + (size_t)node * 128 + cc * 8);
    *(bf16x8*)(Asb + rowl * LDST + cc * 8) = cvt8(p[0], p[1]);
  }
  load_B(Bsb, wt + 3 * 16384, t);  // n_w1a_t
  __syncthreads();

  int lane = t & 63, w = t >> 6;
  int m0 = w * 16, quad = lane >> 4, cix = lane & 15, koff = quad * 8;
  const bf16_t* Arow = Asb + (m0 + cix) * LDST;
  const bf16_t* Bcol = Bsb + cix * LDST;

  f32x4 acc[8];
#pragma unroll
  for (int i = 0; i < 8; ++i) acc[i] = (f32x4){0.f, 0.f, 0.f, 0.f};
  gemm_stripe(Arow, Bcol, koff, acc);  // h @ n_w1a

  __syncthreads();  // Asb/Bsb reads done before restage

  // stage agg tile (f32 -> bf16) from d_out
  for (int i = t; i < 1024; i += 256) {
    int rowl = i >> 4, cc = i & 15;
    int node = node0 + rowl; if (node >= NN) node = NN - 1;
    const float4* p = (const float4*)(agg + (size_t)node * 128 + cc * 8);
    *(bf16x8*)(Asb + rowl * LDST + cc * 8) = cvt8(p[0], p[1]);
  }
  load_B(Bsb, wt + 4 * 16384, t);  // n_w1b_t
  __syncthreads();
  gemm_stripe(Arow, Bcol, koff, acc);  // += agg @ n_w1b

  // u = silu(acc + n_b1) -> Asb (C-layout rows, wave-local)
#pragma unroll
  for (int nt = 0; nt < 8; ++nt) {
    int colg = nt * 16 + cix;
    float b1v = n_b1[colg];
#pragma unroll
    for (int rix = 0; rix < 4; ++rix) {
      float u = siluf(acc[nt][rix] + b1v);
      Asb[(m0 + quad * 4 + rix) * LDST + colg] = (bf16_t)u;
    }
  }
  __syncthreads();
  load_B(Bsb, wt + 5 * 16384, t);  // n_w2t
  __syncthreads();

#pragma unroll
  for (int i = 0; i < 8; ++i) acc[i] = (f32x4){0.f, 0.f, 0.f, 0.f};
  gemm_stripe(Arow, Bcol, koff, acc);  // u @ n_w2

  // h_out = h + . + n_b2  (overwrites agg region; agg for these rows already staged)
#pragma unroll
  for (int nt = 0; nt < 8; ++nt) {
    int colg = nt * 16 + cix;
    float b2v = n_b2[colg];
#pragma unroll
    for (int rix = 0; rix < 4; ++rix) {
      int node = node0 + m0 + quad * 4 + rix;
      if (node < NN) {
        float ho = h[(size_t)node * 128 + colg] + acc[nt][rix] + b2v;
        out[(size_t)node * 128 + colg] = ho;
      }
    }
  }
}

extern "C" void kernel_launch(void* const* d_in, const int* in_sizes, int n_in,
                              void* d_out, int out_size, void* d_ws, size_t ws_size,
                              hipStream_t stream) {
  const float* h = (const float*)d_in[0];
  const float* x = (const float*)d_in[1];
  const int* ei = (const int*)d_in[2];
  const float* eattr = (const float*)d_in[3];
  const float* e_w1 = (const float*)d_in[4];
  const float* e_b1 = (const float*)d_in[5];
  const float* e_w2 = (const float*)d_in[6];
  const float* e_b2 = (const float*)d_in[7];
  const float* n_w1 = (const float*)d_in[8];
  const float* n_b1 = (const float*)d_in[9];
  const float* n_w2 = (const float*)d_in[10];
  const float* n_b2 = (const float*)d_in[11];
  const float* c_w1 = (const float*)d_in[12];
  const float* c_b1 = (const float*)d_in[13];
  const float* c_w2 = (const float*)d_in[14];
  const float* a_w = (const float*)d_in[15];
  const float* a_b = (const float*)d_in[16];

  float* outp = (float*)d_out;
  float* agg = outp;                         // N*128 f32 (h_out region)
  float* coord_agg = outp + (size_t)NN * 128;  // N*3 f32 (x_out region)

  char* ws = (char*)d_ws;
  float* cnt = (float*)(ws + 0);             // N f32 = 200,000 B
  bf16_t* wt = (bf16_t*)(ws + 200000);       // 7*16384 bf16 = 229,376 B

  hipMemsetAsync(d_out, 0, (size_t)(NN * 131) * 4, stream);
  hipMemsetAsync(d_ws, 0, 200000, stream);
  transpose_k<<<7, 256, 0, stream>>>(e_w1, e_w2, n_w1, n_w2, c_w1, wt);
  edge_k<<<NE / 64, 256, 0, stream>>>(h, ei, eattr, x, wt, e_w1, e_b1, e_b2, c_b1,
                                      c_w2, a_w, a_b, agg, coord_agg, cnt);
  node_k<<<(NN + 63) / 64, 256, 0, stream>>>(h, x, wt, n_b1, n_b2, cnt, outp);
}

// Round 4
// 685.930 us; speedup vs baseline: 1.1852x; 1.1852x over previous
//
#include <hip/hip_runtime.h>

// EGNN layer (round 4): exploit linearity of edge-MLP layer 1.
//  - prep_k: pa = h@W1a + e_b1, pb = h@W1b stored bf16 (node-level: 3.3 GFLOP
//    replaces 52.8 GFLOP of edge-level GEMM).
//  - edge_k: z1 = silu(pa[row] + pb[col] + rad*w_rad + ea*w_ea) built directly in
//    registers as the MFMA A-fragment (16B/lane gathers, no LDS staging, no barrier
//    before GEMM1). Only 3 barriers/block (was 8). LDS = 52 KB exactly -> 3 blocks/CU.
//  - agg/coord_agg accumulate in d_out (f32 atomics); node_k finishes in place.
//  - ws = pa + pb + cnt + wt = 26.03 MB (<= 26.6 MB proven safe in round 2 layout).

#define NN 50000
#define NE 800000
#define LDST 136

typedef __bf16 bf16_t;
typedef __bf16 bf16x8 __attribute__((ext_vector_type(8)));
typedef float f32x4 __attribute__((ext_vector_type(4)));

__device__ __forceinline__ float siluf(float v) { return v / (1.f + __expf(-v)); }

// One wave computes a 16-row x 128-col C stripe: C += A(16x128) @ B(128x128).
// A in LDS row-major stride LDST (Arow pre-offset to (m0+cix)*LDST),
// B in LDS transposed [n][k] stride LDST (Bcol pre-offset to cix*LDST).
__device__ __forceinline__ void gemm_stripe(const bf16_t* Arow, const bf16_t* Bcol,
                                            int koff, f32x4 acc[8]) {
#pragma unroll
  for (int ks = 0; ks < 4; ++ks) {
    bf16x8 a = *(const bf16x8*)(Arow + ks * 32 + koff);
#pragma unroll
    for (int nt = 0; nt < 8; ++nt) {
      bf16x8 b = *(const bf16x8*)(Bcol + nt * 16 * LDST + ks * 32 + koff);
      acc[nt] = __builtin_amdgcn_mfma_f32_16x16x32_bf16(a, b, acc[nt], 0, 0, 0);
    }
  }
}

__device__ __forceinline__ void load_B(bf16_t* Bsb, const bf16_t* __restrict__ src, int t) {
  for (int i = t; i < 2048; i += 256) {
    int n = i >> 4, cc = i & 15;
    *(bf16x8*)(Bsb + n * LDST + cc * 8) = *(const bf16x8*)(src + n * 128 + cc * 8);
  }
}

__device__ __forceinline__ bf16x8 cvt8(float4 u0, float4 u1) {
  bf16x8 v;
  v[0] = (bf16_t)u0.x; v[1] = (bf16_t)u0.y; v[2] = (bf16_t)u0.z; v[3] = (bf16_t)u0.w;
  v[4] = (bf16_t)u1.x; v[5] = (bf16_t)u1.y; v[6] = (bf16_t)u1.z; v[7] = (bf16_t)u1.w;
  return v;
}

// ---- transpose 7 128x128 f32 weight blocks into bf16 wt ([n][k] layout) ----
// slots: 0 W1a_t, 1 W1b_t, 2 e_w2t, 3 n_w1a_t, 4 n_w1b_t, 5 n_w2t, 6 c_w1t
__global__ __launch_bounds__(256) void transpose_k(
    const float* __restrict__ e_w1, const float* __restrict__ e_w2,
    const float* __restrict__ n_w1, const float* __restrict__ n_w2,
    const float* __restrict__ c_w1, bf16_t* __restrict__ wt) {
  int b = blockIdx.x;
  const float* src;
  switch (b) {
    case 0: src = e_w1; break;
    case 1: src = e_w1 + 16384; break;
    case 2: src = e_w2; break;
    case 3: src = n_w1; break;
    case 4: src = n_w1 + 16384; break;
    case 5: src = n_w2; break;
    default: src = c_w1; break;
  }
  bf16_t* dst = wt + b * 16384;
  for (int i = threadIdx.x; i < 16384; i += 256) {
    int k = i >> 7, n = i & 127;
    dst[n * 128 + k] = (bf16_t)src[k * 128 + n];
  }
}

// ---- prep: pa = bf16(h@W1a + e_b1), pb = bf16(h@W1b) ----
__global__ __launch_bounds__(256) void prep_k(
    const float* __restrict__ h, const bf16_t* __restrict__ wt,
    const float* __restrict__ e_b1, bf16_t* __restrict__ pa, bf16_t* __restrict__ pb) {
  __shared__ __align__(16) bf16_t Asb[64 * LDST];
  __shared__ __align__(16) bf16_t Bsb[128 * LDST];
  int t = threadIdx.x;
  int node0 = blockIdx.x * 64;
  for (int i = t; i < 1024; i += 256) {
    int rowl = i >> 4, cc = i & 15;
    int node = node0 + rowl; if (node >= NN) node = NN - 1;
    const float4* p = (const float4*)(h + (size_t)node * 128 + cc * 8);
    *(bf16x8*)(Asb + rowl * LDST + cc * 8) = cvt8(p[0], p[1]);
  }
  int lane = t & 63, w = t >> 6;
  int m0 = w * 16, quad = lane >> 4, cix = lane & 15, koff = quad * 8;
  const bf16_t* Arow = Asb + (m0 + cix) * LDST;
  const bf16_t* Bcol = Bsb + cix * LDST;

  bf16_t* outp[2] = {pa, pb};
#pragma unroll
  for (int p = 0; p < 2; ++p) {
    __syncthreads();
    load_B(Bsb, wt + p * 16384, t);
    __syncthreads();
    f32x4 acc[8];
#pragma unroll
    for (int i = 0; i < 8; ++i) acc[i] = (f32x4){0.f, 0.f, 0.f, 0.f};
    gemm_stripe(Arow, Bcol, koff, acc);
#pragma unroll
    for (int nt = 0; nt < 8; ++nt) {
      int colg = nt * 16 + cix;
      float bv = p == 0 ? e_b1[colg] : 0.f;
#pragma unroll
      for (int rix = 0; rix < 4; ++rix) {
        int node = node0 + m0 + quad * 4 + rix;
        if (node < NN) outp[p][(size_t)node * 128 + colg] = (bf16_t)(acc[nt][rix] + bv);
      }
    }
  }
}

// ---- edge kernel: 64 edges per block, 3 barriers ----
__global__ __launch_bounds__(256) void edge_k(
    const bf16_t* __restrict__ pa, const bf16_t* __restrict__ pb,
    const int* __restrict__ ei, const float* __restrict__ eattr,
    const float* __restrict__ x, const bf16_t* __restrict__ wt,
    const float* __restrict__ e_w1, const float* __restrict__ e_b2,
    const float* __restrict__ c_b1, const float* __restrict__ c_w2,
    const float* __restrict__ a_w, const float* __restrict__ a_b,
    float* __restrict__ agg, float* __restrict__ coord_agg, float* __restrict__ cnt) {
  __shared__ __align__(16) bf16_t Ag[64 * LDST];    // 17408 B (m staging)
  __shared__ __align__(16) bf16_t Bsb[128 * LDST];  // 34816 B
  __shared__ int rows_s[64];
  __shared__ int cols_s[64];
  __shared__ float rad_s[64];
  __shared__ float ea_s[64];                        // total 53248 B

  int t = threadIdx.x;
  int e0 = blockIdx.x * 64;

  if (t < 64) {
    int eg = e0 + t;
    int r = ei[eg], c = ei[NE + eg];
    rows_s[t] = r; cols_s[t] = c;
    float d0 = x[r * 3 + 0] - x[c * 3 + 0];
    float d1 = x[r * 3 + 1] - x[c * 3 + 1];
    float d2 = x[r * 3 + 2] - x[c * 3 + 2];
    rad_s[t] = d0 * d0 + d1 * d1 + d2 * d2;
    ea_s[t] = eattr[eg];
  }
  load_B(Bsb, wt + 2 * 16384, t);  // e_w2t
  __syncthreads();                 // [1]

  int lane = t & 63, w = t >> 6;
  int m0 = w * 16, quad = lane >> 4, cix = lane & 15, koff = quad * 8;
  const bf16_t* Bcol = Bsb + cix * LDST;

  // z1 built in-register as A-fragment; GEMM1 = z1 @ e_w2 fused
  int e = m0 + cix;
  int r = rows_s[e], c = cols_s[e];
  float rad = rad_s[e], ea = ea_s[e];
  const bf16_t* par = pa + (size_t)r * 128;
  const bf16_t* pbr = pb + (size_t)c * 128;
  const float* wrp = e_w1 + 256 * 128;
  const float* wep = e_w1 + 257 * 128;

  f32x4 acc[8];
#pragma unroll
  for (int i = 0; i < 8; ++i) acc[i] = (f32x4){0.f, 0.f, 0.f, 0.f};
#pragma unroll
  for (int ks = 0; ks < 4; ++ks) {
    int kk = ks * 32 + koff;
    bf16x8 pa8 = *(const bf16x8*)(par + kk);
    bf16x8 pb8 = *(const bf16x8*)(pbr + kk);
    float4 wr0 = *(const float4*)(wrp + kk);
    float4 wr1 = *(const float4*)(wrp + kk + 4);
    float4 we0 = *(const float4*)(wep + kk);
    float4 we1 = *(const float4*)(wep + kk + 4);
    float wrv[8] = {wr0.x, wr0.y, wr0.z, wr0.w, wr1.x, wr1.y, wr1.z, wr1.w};
    float wev[8] = {we0.x, we0.y, we0.z, we0.w, we1.x, we1.y, we1.z, we1.w};
    bf16x8 af;
#pragma unroll
    for (int j = 0; j < 8; ++j) {
      float z = (float)pa8[j] + (float)pb8[j] + rad * wrv[j] + ea * wev[j];
      af[j] = (bf16_t)siluf(z);
    }
#pragma unroll
    for (int nt = 0; nt < 8; ++nt) {
      bf16x8 b = *(const bf16x8*)(Bcol + nt * 16 * LDST + kk);
      acc[nt] = __builtin_amdgcn_mfma_f32_16x16x32_bf16(af, b, acc[nt], 0, 0, 0);
    }
  }

  // m = silu(. + b2); att = sigmoid(m . a_w + a_b); m *= att; m -> Ag (bf16)
  float attp[4] = {0.f, 0.f, 0.f, 0.f};
#pragma unroll
  for (int nt = 0; nt < 8; ++nt) {
    int colg = nt * 16 + cix;
    float b2v = e_b2[colg];
    float awv = a_w[colg];
#pragma unroll
    for (int rix = 0; rix < 4; ++rix) {
      float v = siluf(acc[nt][rix] + b2v);
      acc[nt][rix] = v;
      attp[rix] += v * awv;
    }
  }
  float a_bv = a_b[0];
  float attv[4];
#pragma unroll
  for (int rix = 0; rix < 4; ++rix) {
    float s = attp[rix];
    s += __shfl_xor(s, 1); s += __shfl_xor(s, 2);
    s += __shfl_xor(s, 4); s += __shfl_xor(s, 8);
    attv[rix] = 1.f / (1.f + __expf(-(s + a_bv)));
  }
#pragma unroll
  for (int nt = 0; nt < 8; ++nt) {
#pragma unroll
    for (int rix = 0; rix < 4; ++rix) {
      float v = acc[nt][rix] * attv[rix];
      Ag[(m0 + quad * 4 + rix) * LDST + nt * 16 + cix] = (bf16_t)v;
    }
  }

  __syncthreads();                 // [2] all m rows written; Bsb readers done
  load_B(Bsb, wt + 6 * 16384, t);  // c_w1t
  __syncthreads();                 // [3]

  const bf16_t* Arow = Ag + (m0 + cix) * LDST;
#pragma unroll
  for (int i = 0; i < 8; ++i) acc[i] = (f32x4){0.f, 0.f, 0.f, 0.f};
  gemm_stripe(Arow, Bcol, koff, acc);  // m @ c_w1

  float cup[4] = {0.f, 0.f, 0.f, 0.f};
#pragma unroll
  for (int nt = 0; nt < 8; ++nt) {
    int colg = nt * 16 + cix;
    float cb1v = c_b1[colg];
    float cw2v = c_w2[colg];
#pragma unroll
    for (int rix = 0; rix < 4; ++rix) {
      cup[rix] += siluf(acc[nt][rix] + cb1v) * cw2v;
    }
  }
#pragma unroll
  for (int rix = 0; rix < 4; ++rix) {
    float s = cup[rix];
    s += __shfl_xor(s, 1); s += __shfl_xor(s, 2);
    s += __shfl_xor(s, 4); s += __shfl_xor(s, 8);
    cup[rix] = s;
  }
  if (cix == 0) {
#pragma unroll
    for (int rix = 0; rix < 4; ++rix) {
      int ee = m0 + quad * 4 + rix;
      int rr = rows_s[ee], cc = cols_s[ee];
      float cu = cup[rix];
#pragma unroll
      for (int d = 0; d < 3; ++d) {
        float cd = x[rr * 3 + d] - x[cc * 3 + d];
        atomicAdd(&coord_agg[rr * 3 + d], cd * cu);
      }
      atomicAdd(&cnt[rr], 1.0f);
    }
  }

  // scatter gated m into agg (f32 atomics, wave-coalesced rows)
#pragma unroll
  for (int it = 0; it < 32; ++it) {
    int idx = it * 256 + t;
    int ee = idx >> 7, f = idx & 127;
    float v = (float)Ag[ee * LDST + f];
    atomicAdd(&agg[(size_t)rows_s[ee] * 128 + f], v);
  }
}

// ---- node kernel (in-place on d_out) ----
__global__ __launch_bounds__(256) void node_k(
    const float* __restrict__ h, const float* __restrict__ x,
    const bf16_t* __restrict__ wt, const float* __restrict__ n_b1,
    const float* __restrict__ n_b2, const float* __restrict__ cnt,
    float* __restrict__ out) {
  __shared__ __align__(16) bf16_t Asb[64 * LDST];
  __shared__ __align__(16) bf16_t Bsb[128 * LDST];
  int t = threadIdx.x;
  int node0 = blockIdx.x * 64;
  const float* agg = out;                // accumulated by edge_k
  float* xout = out + (size_t)NN * 128;  // holds coord_agg on entry

  if (t < 192) {
    int node = node0 + t / 3;
    int d = t - (t / 3) * 3;
    if (node < NN) {
      float c = cnt[node];
      float denom = c > 1.f ? c : 1.f;
      float xo = x[node * 3 + d] + xout[node * 3 + d] / denom;
      xout[node * 3 + d] = xo;
    }
  }

  for (int i = t; i < 1024; i += 256) {
    int rowl = i >> 4, cc = i & 15;
    int node = node0 + rowl; if (node >= NN) node = NN - 1;
    const float4* p = (const float4*)(h + (size_t)node * 128 + cc * 8);
    *(bf16x8*)(Asb + rowl * LDST + cc * 8) = cvt8(p[0], p[1]);
  }
  load_B(Bsb, wt + 3 * 16384, t);  // n_w1a_t
  __syncthreads();

  int lane = t & 63, w = t >> 6;
  int m0 = w * 16, quad = lane >> 4, cix = lane & 15, koff = quad * 8;
  const bf16_t* Arow = Asb + (m0 + cix) * LDST;
  const bf16_t* Bcol = Bsb + cix * LDST;

  f32x4 acc[8];
#pragma unroll
  for (int i = 0; i < 8; ++i) acc[i] = (f32x4){0.f, 0.f, 0.f, 0.f};
  gemm_stripe(Arow, Bcol, koff, acc);  // h @ n_w1a

  __syncthreads();

  for (int i = t; i < 1024; i += 256) {
    int rowl = i >> 4, cc = i & 15;
    int node = node0 + rowl; if (node >= NN) node = NN - 1;
    const float4* p = (const float4*)(agg + (size_t)node * 128 + cc * 8);
    *(bf16x8*)(Asb + rowl * LDST + cc * 8) = cvt8(p[0], p[1]);
  }
  load_B(Bsb, wt + 4 * 16384, t);  // n_w1b_t
  __syncthreads();
  gemm_stripe(Arow, Bcol, koff, acc);  // += agg @ n_w1b

#pragma unroll
  for (int nt = 0; nt < 8; ++nt) {
    int colg = nt * 16 + cix;
    float b1v = n_b1[colg];
#pragma unroll
    for (int rix = 0; rix < 4; ++rix) {
      float u = siluf(acc[nt][rix] + b1v);
      Asb[(m0 + quad * 4 + rix) * LDST + colg] = (bf16_t)u;
    }
  }
  __syncthreads();
  load_B(Bsb, wt + 5 * 16384, t);  // n_w2t
  __syncthreads();

#pragma unroll
  for (int i = 0; i < 8; ++i) acc[i] = (f32x4){0.f, 0.f, 0.f, 0.f};
  gemm_stripe(Arow, Bcol, koff, acc);  // u @ n_w2

#pragma unroll
  for (int nt = 0; nt < 8; ++nt) {
    int colg = nt * 16 + cix;
    float b2v = n_b2[colg];
#pragma unroll
    for (int rix = 0; rix < 4; ++rix) {
      int node = node0 + m0 + quad * 4 + rix;
      if (node < NN) {
        float ho = h[(size_t)node * 128 + colg] + acc[nt][rix] + b2v;
        out[(size_t)node * 128 + colg] = ho;
      }
    }
  }
}

extern "C" void kernel_launch(void* const* d_in, const int* in_sizes, int n_in,
                              void* d_out, int out_size, void* d_ws, size_t ws_size,
                              hipStream_t stream) {
  const float* h = (const float*)d_in[0];
  const float* x = (const float*)d_in[1];
  const int* ei = (const int*)d_in[2];
  const float* eattr = (const float*)d_in[3];
  const float* e_w1 = (const float*)d_in[4];
  const float* e_b1 = (const float*)d_in[5];
  const float* e_w2 = (const float*)d_in[6];
  const float* e_b2 = (const float*)d_in[7];
  const float* n_w1 = (const float*)d_in[8];
  const float* n_b1 = (const float*)d_in[9];
  const float* n_w2 = (const float*)d_in[10];
  const float* n_b2 = (const float*)d_in[11];
  const float* c_w1 = (const float*)d_in[12];
  const float* c_b1 = (const float*)d_in[13];
  const float* c_w2 = (const float*)d_in[14];
  const float* a_w = (const float*)d_in[15];
  const float* a_b = (const float*)d_in[16];

  float* outp = (float*)d_out;
  float* agg = outp;                           // N*128 f32 (h_out region)
  float* coord_agg = outp + (size_t)NN * 128;  // N*3 f32 (x_out region)

  // ws layout: pa 12.8MB | pb 12.8MB | cnt 200KB | wt 229KB = 26.03 MB total
  char* ws = (char*)d_ws;
  bf16_t* pa = (bf16_t*)(ws + 0);
  bf16_t* pb = (bf16_t*)(ws + 12800000);
  float* cnt = (float*)(ws + 25600000);
  bf16_t* wt = (bf16_t*)(ws + 25800000);

  hipMemsetAsync(d_out, 0, (size_t)(NN * 131) * 4, stream);
  hipMemsetAsync(ws + 25600000, 0, 200000, stream);
  transpose_k<<<7, 256, 0, stream>>>(e_w1, e_w2, n_w1, n_w2, c_w1, wt);
  prep_k<<<(NN + 63) / 64, 256, 0, stream>>>(h, wt, e_b1, pa, pb);
  edge_k<<<NE / 64, 256, 0, stream>>>(pa, pb, ei, eattr, x, wt, e_w1, e_b2, c_b1,
                                      c_w2, a_w, a_b, agg, coord_agg, cnt);
  node_k<<<(NN + 63) / 64, 256, 0, stream>>>(h, x, wt, n_b1, n_b2, cnt, outp);
}